// Round 4
// baseline (239.539 us; speedup 1.0000x reference)
//
#include <hip/hip_runtime.h>

// KnowledgeConsistentAttention: out = softmax_q( pool3x3(F) . K^T ) . K,  K = normalize(F+eps)
// pool3x3 acts only on the p index of S = F.K^T => flash-style fused kernel with
// Q=G=pool3x3(F), K=V=normalize(F+eps). exp(S) fits fp32 -> no max subtraction.
//
// R4: V is read as pre-interleaved MFMA fragments straight from global (L1/L2-served,
// perfectly coalesced 1KB/instr) -- no ldsV, no V DMA. K stays LDS double-buffered
// (1 barrier/tile, stage-ahead). rt=1 (16p/wave) + launch_bounds(256,3) -> 12 waves/CU.

#define EPSV 1e-7f

typedef __bf16 bf16x8 __attribute__((ext_vector_type(8)));
typedef float f32x4 __attribute__((ext_vector_type(4)));

__device__ __forceinline__ unsigned short f2bf(float f) {
    union { float f; unsigned int u; } x; x.f = f;
    unsigned int r = x.u + 0x7FFFu + ((x.u >> 16) & 1u);
    return (unsigned short)(r >> 16);
}

__device__ __forceinline__ f32x4 mfma16(bf16x8 a, bf16x8 b, f32x4 c) {
    return __builtin_amdgcn_mfma_f32_16x16x32_bf16(a, b, c, 0, 0, 0);
}

__device__ __forceinline__ void gload_lds16(const void* g, void* l) {
    __builtin_amdgcn_global_load_lds((const __attribute__((address_space(1))) void*)g,
                                     (__attribute__((address_space(3))) void*)l, 16, 0, 0);
}

// ---------------- prep 1: K_hi (bf16 normalized rows) + Vt2 (fragment-interleaved) -------
// Vt2 layout: per (b, tile t of 32 q, c16 of 16 channels): 1KB chunk; lane l = g4*16+l15
// holds V[c16*16+l15][t*32 + g4*8 .. +7] as 16B. GEMM2's A-frag = one coalesced b128/lane.
__global__ __launch_bounds__(256) void prep_kv(const float* __restrict__ F,
                                               unsigned short* __restrict__ Khi,
                                               unsigned short* __restrict__ Vt2) {
    __shared__ unsigned short ldsT[256 * 72];  // [c][64q + pad], rows 144B
    const int tid = threadIdx.x;
    const int w = tid >> 6, lane = tid & 63;
    const int q0 = blockIdx.x * 64;
    const int b = blockIdx.y;
    const size_t bq = (size_t)b * 4096;

    for (int r = 0; r < 16; ++r) {
        const int qloc = w * 16 + r;
        const int q = q0 + qloc;
        const float4 f = *(const float4*)(F + ((bq + q) << 8) + lane * 4);
        float v0 = f.x + EPSV, v1 = f.y + EPSV, v2 = f.z + EPSV, v3 = f.w + EPSV;
        float ss = v0 * v0 + v1 * v1 + v2 * v2 + v3 * v3;
        #pragma unroll
        for (int m = 1; m <= 32; m <<= 1) ss += __shfl_xor(ss, m);
        const float inv = 1.0f / sqrtf(ss);
        const unsigned short k0 = f2bf(v0 * inv), k1 = f2bf(v1 * inv);
        const unsigned short k2 = f2bf(v2 * inv), k3 = f2bf(v3 * inv);
        ushort4 kk; kk.x = k0; kk.y = k1; kk.z = k2; kk.w = k3;
        *(ushort4*)(Khi + ((bq + q) << 8) + lane * 4) = kk;
        ldsT[(lane * 4 + 0) * 72 + qloc] = k0;
        ldsT[(lane * 4 + 1) * 72 + qloc] = k1;
        ldsT[(lane * 4 + 2) * 72 + qloc] = k2;
        ldsT[(lane * 4 + 3) * 72 + qloc] = k3;
    }
    __syncthreads();
    // write Vt2 fragments: thread owns channel c = tid; block covers tiles 2*blockIdx.x, +1
    const int c = tid;
    const size_t tbase = (size_t)b * 128 + (size_t)blockIdx.x * 2;
    #pragma unroll
    for (int tsub = 0; tsub < 2; ++tsub)
        #pragma unroll
        for (int g4 = 0; g4 < 4; ++g4) {
            *(uint4*)((char*)Vt2 + ((tbase + tsub) << 14) + ((c >> 4) << 10) +
                      ((g4 * 16 + (c & 15)) << 4)) =
                *(const uint4*)((const char*)ldsT + c * 144 + tsub * 64 + g4 * 16);
        }
}

// ---------------- prep 2: G = pool3x3(F) * 9/cnt (TF SAME), separable, bf16 ----------------
__global__ __launch_bounds__(256) void prep_g(const float* __restrict__ F,
                                              unsigned short* __restrict__ G) {
    __shared__ float vs[64 * 256];
    const int tid = threadIdx.x;
    const int i = blockIdx.x, b = blockIdx.y;
    const size_t bq = (size_t)b * 4096;
    const int i0 = i > 0 ? i - 1 : 0, i1 = i < 63 ? i + 1 : 63;
    #pragma unroll
    for (int k2 = 0; k2 < 16; ++k2) {
        const int cell = k2 * 256 + tid;
        const int j = cell >> 6, c4 = (cell & 63) << 2;
        float4 acc = {0.f, 0.f, 0.f, 0.f};
        for (int ii = i0; ii <= i1; ++ii) {
            const float4 f = *(const float4*)(F + ((bq + ii * 64 + j) << 8) + c4);
            acc.x += f.x; acc.y += f.y; acc.z += f.z; acc.w += f.w;
        }
        *(float4*)(vs + j * 256 + c4) = acc;
    }
    __syncthreads();
    const float ri = (float)(i1 - i0 + 1);
    #pragma unroll
    for (int k2 = 0; k2 < 16; ++k2) {
        const int cell = k2 * 256 + tid;
        const int j = cell >> 6, c4 = (cell & 63) << 2;
        const int j0 = j > 0 ? j - 1 : 0, j1 = j < 63 ? j + 1 : 63;
        float4 s = {0.f, 0.f, 0.f, 0.f};
        for (int jj = j0; jj <= j1; ++jj) {
            const float4 v = *(const float4*)(vs + jj * 256 + c4);
            s.x += v.x; s.y += v.y; s.z += v.z; s.w += v.w;
        }
        const float scale = 9.0f / (ri * (float)(j1 - j0 + 1));
        ushort4 gv; gv.x = f2bf(s.x * scale); gv.y = f2bf(s.y * scale);
        gv.z = f2bf(s.z * scale); gv.w = f2bf(s.w * scale);
        *(ushort4*)(G + ((bq + i * 64 + j) << 8) + c4) = gv;
    }
}

// ---------------- main fused attention ----------------
// grid 1024 (XCD-swizzled -> pb[64] x split[4] x b[4]), 256 threads (4 waves, 16p each).
// Per 32q tile: K staged to LDS (dbuf, 1 barrier); S = G@K^T (A=G in regs); exp -> P via
// per-wave LDS bounce; O^T += V@P with V-frags loaded straight from global Vt2 (coalesced,
// L1-cached, software-pipelined 8 deep).
template <int ATOMIC>
__global__ __launch_bounds__(256, 3) void attn_main(
        const unsigned short* __restrict__ Khi, const unsigned short* __restrict__ Vt2,
        const unsigned short* __restrict__ G, float* __restrict__ wsl,
        float* __restrict__ dOut, float* __restrict__ wsO) {
    __shared__ unsigned short ldsK[2][32 * 256];  // 2 x 16KB, granule-XOR swizzle
    __shared__ unsigned short ldsP[4][16 * 40];   // 5KB, per-wave P bounce, 80B rows
    const int tid = threadIdx.x;
    const int w = tid >> 6, lane = tid & 63;
    const int l15 = lane & 15, g4 = lane >> 4;

    // XCD-aware decomposition: each XCD owns 2 (split,b) groups x 64 pb
    const int bid = blockIdx.x;
    const int u = bid & 7, v = bid >> 3;
    const int group = u * 2 + (v >> 6);
    const int pb = v & 63;
    const int split = group >> 2, b = group & 3;

    const int pw = pb * 64 + w * 16;
    const size_t bq = (size_t)b * 4096;

    const char* KhiB = (const char*)Khi + ((bq + split * 1024) << 9);
    const char* Vt2B = (const char*)Vt2 + (((size_t)b * 128 + split * 32) << 14) + lane * 16;

    // prologue: stage K tile 0 into buf 0
    #pragma unroll
    for (int it = 0; it < 4; ++it) {
        const int g = it * 256 + tid;
        const int row = g >> 5, pos = g & 31;
        gload_lds16(KhiB + row * 512 + ((pos ^ (row & 7)) << 4),
                    (char*)&ldsK[0][0] + g * 16);
    }

    // preload G A-frags: 16 rows x 256 k per wave -> 32 VGPRs
    bf16x8 a[8];
    #pragma unroll
    for (int kg = 0; kg < 8; ++kg)
        a[kg] = *(const bf16x8*)(G + ((bq + pw + l15) << 8) + (kg << 5) + (g4 << 3));

    f32x4 o[16];
    float lacc[4];
    #pragma unroll
    for (int c16 = 0; c16 < 16; ++c16) o[c16] = f32x4{0.f, 0.f, 0.f, 0.f};
    #pragma unroll
    for (int r = 0; r < 4; ++r) lacc[r] = 0.f;
    unsigned short* Pw = &ldsP[w][0];

    __syncthreads();  // K(0) landed

    #pragma unroll 1
    for (int t = 0; t < 32; ++t) {
        const int cur = t & 1;

        // issue stage of K(t+1) (drained by end-of-iter barrier, a full tile away)
        if (t < 31) {
            const char* ks = KhiB + (size_t)(t + 1) * 16384;
            #pragma unroll
            for (int it = 0; it < 4; ++it) {
                const int g = it * 256 + tid;
                const int row = g >> 5, pos = g & 31;
                gload_lds16(ks + row * 512 + ((pos ^ (row & 7)) << 4),
                            (char*)&ldsK[cur ^ 1][0] + g * 16);
            }
        }

        // issue first 8 V-fragments (c16 0..7) from global -- consumed in GEMM2
        const char* vt = Vt2B + ((size_t)t << 14);
        bf16x8 bva[8];
        #pragma unroll
        for (int g = 0; g < 8; ++g)
            bva[g] = *(const bf16x8*)(vt + g * 1024);

        // ---- GEMM1: S[16p x 32q] ----
        f32x4 s[2];
        s[0] = f32x4{0.f, 0.f, 0.f, 0.f};
        s[1] = f32x4{0.f, 0.f, 0.f, 0.f};
        __builtin_amdgcn_s_setprio(1);
        #pragma unroll
        for (int kg = 0; kg < 8; ++kg) {
            #pragma unroll
            for (int ct = 0; ct < 2; ++ct) {
                const int qr = ct * 16 + l15;
                const bf16x8 bk = *(const bf16x8*)((const char*)&ldsK[cur][0] + (qr << 9) +
                                    ((((kg << 2) + g4)) ^ (qr & 7)) * 16);
                s[ct] = mfma16(a[kg], bk, s[ct]);
            }
        }
        __builtin_amdgcn_s_setprio(0);

        // ---- exp + l accum + P -> per-wave LDS (S layout: p-sub = g4*4+r, q = ct*16+l15) --
        #pragma unroll
        for (int ct = 0; ct < 2; ++ct)
            #pragma unroll
            for (int r = 0; r < 4; ++r) {
                const float e = __expf(s[ct][r]);
                lacc[r] += e;
                Pw[(g4 * 4 + r) * 40 + ct * 16 + l15] = f2bf(e);
            }

        // ---- GEMM2 (O^T): A = V-frag (global), B = P-frag (LDS) ----
        const bf16x8 a2 = *(const bf16x8*)((const char*)Pw + l15 * 80 + (g4 << 4));
        __builtin_amdgcn_s_setprio(1);
        #pragma unroll
        for (int g = 0; g < 8; ++g) {
            o[g] = mfma16(bva[g], a2, o[g]);
            bva[g] = *(const bf16x8*)(vt + (g + 8) * 1024);
        }
        #pragma unroll
        for (int g = 0; g < 8; ++g)
            o[g + 8] = mfma16(bva[g], a2, o[g + 8]);
        __builtin_amdgcn_s_setprio(0);

        if (t < 31) __syncthreads();  // K(t+1) staged + buffer handoff
    }

    // ---- epilogue: reduce l across 16 q-columns ----
    #pragma unroll
    for (int r = 0; r < 4; ++r) {
        float vsum = lacc[r];
        #pragma unroll
        for (int m = 1; m <= 8; m <<= 1) vsum += __shfl_xor(vsum, m);
        lacc[r] = vsum;
    }
    if (l15 == 0) {
        #pragma unroll
        for (int r = 0; r < 4; ++r)
            wsl[(size_t)split * 16384 + bq + pw + g4 * 4 + r] = lacc[r];
    }

    // O^T D-layout: p = pw + l15, c = c16*16 + g4*4 + r -> float4 coalesced stores
    if (!ATOMIC) {
        float* dst = (split == 0) ? dOut : (wsO + (size_t)(split - 1) * 4194304);
        #pragma unroll
        for (int c16 = 0; c16 < 16; ++c16)
            *(f32x4*)(dst + ((bq + pw + l15) << 8) + c16 * 16 + (g4 << 2)) = o[c16];
    } else {
        #pragma unroll
        for (int c16 = 0; c16 < 16; ++c16)
            #pragma unroll
            for (int r = 0; r < 4; ++r) {
                const size_t idx = ((bq + pw + l15) << 8) + c16 * 16 + (g4 << 2) + r;
                atomicAdd(&dOut[idx], o[c16][r]);
            }
    }
}

// ---------------- finalize: sum q-split partials, divide by l ----------------
__global__ __launch_bounds__(256) void reduce_fin(float* __restrict__ dOut,
                                                  const float* __restrict__ wsO,
                                                  const float* __restrict__ wsl) {
    const int i4 = blockIdx.x * 256 + threadIdx.x;
    const int row = i4 >> 6;
    const float l = wsl[row] + wsl[16384 + row] + wsl[32768 + row] + wsl[49152 + row];
    const float inv = 1.0f / l;
    float4 v = ((const float4*)dOut)[i4];
    const float4 a = ((const float4*)wsO)[i4];
    const float4 b = ((const float4*)(wsO + 4194304))[i4];
    const float4 c = ((const float4*)(wsO + 8388608))[i4];
    v.x = (v.x + a.x + b.x + c.x) * inv;
    v.y = (v.y + a.y + b.y + c.y) * inv;
    v.z = (v.z + a.z + b.z + c.z) * inv;
    v.w = (v.w + a.w + b.w + c.w) * inv;
    ((float4*)dOut)[i4] = v;
}

__global__ __launch_bounds__(256) void divide_fin(float* __restrict__ dOut,
                                                  const float* __restrict__ wsl) {
    const int i4 = blockIdx.x * 256 + threadIdx.x;
    const int row = i4 >> 6;
    const float l = wsl[row] + wsl[16384 + row] + wsl[32768 + row] + wsl[49152 + row];
    const float inv = 1.0f / l;
    float4 v = ((const float4*)dOut)[i4];
    v.x *= inv; v.y *= inv; v.z *= inv; v.w *= inv;
    ((float4*)dOut)[i4] = v;
}

extern "C" void kernel_launch(void* const* d_in, const int* in_sizes, int n_in,
                              void* d_out, int out_size, void* d_ws, size_t ws_size,
                              hipStream_t stream) {
    const float* F = (const float*)d_in[0];
    // d_in[1] (masks) has no effect on the output.
    float* out = (float*)d_out;
    char* ws = (char*)d_ws;

    // ws layout: Khi bf16 [4][4096][256] @0 (8MB) | Vt2 bf16 frag-interleaved (8MB) @8MB |
    //            G bf16 [4][4096][256] @16MB | wsl f32 [4][16384] @24MB (256KB) |
    //            wsO f32 3x[4][4096][256] @24.25MB (48MB)
    unsigned short* Khi = (unsigned short*)ws;
    unsigned short* Vt2 = Khi + 4194304;
    unsigned short* G = Vt2 + 4194304;
    float* wsl = (float*)(ws + 25165824);
    float* wsO = (float*)(ws + 25165824 + 262144);
    const size_t needA = 25165824u + 262144u + 3u * 16777216u;

    prep_kv<<<dim3(64, 4), 256, 0, stream>>>(F, Khi, Vt2);
    prep_g<<<dim3(64, 4), 256, 0, stream>>>(F, G);

    if (ws_size >= needA) {
        attn_main<0><<<dim3(1024), 256, 0, stream>>>(Khi, Vt2, G, wsl, out, wsO);
        reduce_fin<<<4096, 256, 0, stream>>>(out, wsO, wsl);
    } else {
        hipMemsetAsync(out, 0, 16777216, stream);
        attn_main<1><<<dim3(1024), 256, 0, stream>>>(Khi, Vt2, G, wsl, out, nullptr);
        divide_fin<<<4096, 256, 0, stream>>>(out, wsl);
    }
}